// Round 1
// 151.891 us; speedup vs baseline: 1.0044x; 1.0044x over previous
//
#include <hip/hip_runtime.h>

#define NUMW 4096
#define IN_F 100
#define HID  30

typedef float float4n __attribute__((ext_vector_type(4)));

// ---------- stage 1: A = relu(oo@Wp+bp); P = A@W1; Qb = A@W2 + bc ----------
// 512 blocks x 256 threads, 8 rows/block.
__global__ __launch_bounds__(256) void stage1(
    const float* __restrict__ oo,
    const float* __restrict__ Wp,
    const float* __restrict__ bp,
    const float* __restrict__ Wc,
    const float* __restrict__ bc,
    float* __restrict__ Pbuf, float* __restrict__ Qbuf)
{
    __shared__ float Wp_s[IN_F * HID];   // 12 KB
    __shared__ float oo_s[8][IN_F];      // 3.2 KB
    __shared__ float A_s[8 * HID];       // 0.96 KB
    __shared__ float Wc_s[2 * HID * 2];  // 480 B
    __shared__ float bc_s[2];
    const int tid = threadIdx.x;
    const int i0  = blockIdx.x * 8;

    for (int t = tid; t < IN_F * HID; t += 256) Wp_s[t] = Wp[t];
    if (tid < 2 * HID * 2) Wc_s[tid] = Wc[tid];
    if (tid >= 120 && tid < 122) bc_s[tid - 120] = bc[tid - 120];

    const float4* oo4 = (const float4*)oo;
    for (int t = tid; t < 8 * 25; t += 256) {
        int r = t / 25, c = t % 25;
        float4 v = oo4[(size_t)(i0 + r) * 25 + c];
        oo_s[r][4 * c]     = v.x;
        oo_s[r][4 * c + 1] = v.y;
        oo_s[r][4 * c + 2] = v.z;
        oo_s[r][4 * c + 3] = v.w;
    }
    __syncthreads();

    if (tid < 8 * HID) {
        int r = tid / HID, h = tid % HID;
        float a0 = bp[h], a1 = 0.f;
        #pragma unroll
        for (int k = 0; k < IN_F; k += 2) {
            a0 += oo_s[r][k]     * Wp_s[k * HID + h];
            a1 += oo_s[r][k + 1] * Wp_s[(k + 1) * HID + h];
        }
        float a = a0 + a1;
        A_s[r * HID + h] = a > 0.f ? a : 0.f;
    }
    __syncthreads();

    // P/Q tail: 64 threads = 8 rows x {c, isQ, half}. Each lane does a 15-dot,
    // halves combined via shfl_xor(4). Wc/bc come from LDS (no global loads).
    if (tid < 64) {
        int r    = tid >> 3;
        int q    = tid & 7;
        int c    = q & 1, isQ = (q >> 1) & 1, half = q >> 2;
        int hbase = half * 15;
        int hoff  = isQ * HID + hbase;
        float acc = 0.f;
        #pragma unroll
        for (int hh = 0; hh < 15; ++hh)
            acc += A_s[r * HID + hbase + hh] * Wc_s[(hoff + hh) * 2 + c];
        acc += __shfl_xor(acc, 4);   // combine the two 15-dot halves
        if (half == 0) {
            int i = i0 + r;
            if (isQ) Qbuf[i * 2 + c] = acc + bc_s[c];
            else     Pbuf[i * 2 + c] = acc;
        }
    }
}

// ---------- stage 2: out[i,j,c] = relu(P[i,c] + Qb[j,c]), f32 output ----------
// grid (4, 512) x 256 threads. Thread: two j-chunks (jA, jA+512), 2 j's each
// (float4 = 16 B lane-consecutive -> every store instr covers 1 KB contiguous),
// x 8 i rows. Halves the uniform Pbuf loads per stored byte vs 16-row variant.
// Plain stores (no nt): match the 6.4 TB/s fill-kernel store path.
__global__ __launch_bounds__(256) void stage2(
    const float* __restrict__ Pbuf, const float* __restrict__ Qbuf,
    float* __restrict__ out)
{
    const int tid = threadIdx.x;
    const int jA  = blockIdx.x * 1024 + tid * 2;  // first j-chunk
    const int jB  = jA + 512;                     // second j-chunk
    const int i0  = blockIdx.y * 8;

    float4n qa = *(const float4n*)(Qbuf + (size_t)jA * 2);  // Qb[jA], Qb[jA+1]
    float4n qb = *(const float4n*)(Qbuf + (size_t)jB * 2);  // Qb[jB], Qb[jB+1]

    #pragma unroll
    for (int r = 0; r < 8; ++r) {
        int i = i0 + r;
        float p0 = Pbuf[i * 2], p1 = Pbuf[i * 2 + 1];  // block-uniform -> broadcast
        float4n oa, ob;
        oa.x = fmaxf(p0 + qa.x, 0.f);
        oa.y = fmaxf(p1 + qa.y, 0.f);
        oa.z = fmaxf(p0 + qa.z, 0.f);
        oa.w = fmaxf(p1 + qa.w, 0.f);
        ob.x = fmaxf(p0 + qb.x, 0.f);
        ob.y = fmaxf(p1 + qb.y, 0.f);
        ob.z = fmaxf(p0 + qb.z, 0.f);
        ob.w = fmaxf(p1 + qb.w, 0.f);
        float* dst = out + (size_t)i * (NUMW * 2);
        *(float4n*)(dst + (size_t)jA * 2) = oa;
        *(float4n*)(dst + (size_t)jB * 2) = ob;
    }
}

extern "C" void kernel_launch(void* const* d_in, const int* in_sizes, int n_in,
                              void* d_out, int out_size, void* d_ws, size_t ws_size,
                              hipStream_t stream) {
    const float* oo = (const float*)d_in[0];
    const float* Wp = (const float*)d_in[1];
    const float* bp = (const float*)d_in[2];
    const float* Wc = (const float*)d_in[3];
    const float* bc = (const float*)d_in[4];

    float* Pbuf = (float*)d_ws;              // 4096*2 f32
    float* Qbuf = Pbuf + NUMW * 2;           // 4096*2 f32 (bc folded in)

    stage1<<<dim3(NUMW / 8), 256, 0, stream>>>(oo, Wp, bp, Wc, bc, Pbuf, Qbuf);
    stage2<<<dim3(4, 512), 256, 0, stream>>>(Pbuf, Qbuf, (float*)d_out);
}